// Round 5
// baseline (471.839 us; speedup 1.0000x reference)
//
#include <hip/hip_runtime.h>
#include <stdint.h>

#define LBL 50
#define NL 52
#define L2E 1.4426950408889634f
#define BB 128
#define SS 512
#define DD 1024

typedef __attribute__((ext_vector_type(8))) short short8;
typedef __attribute__((ext_vector_type(4))) float float4v;

union S8U { unsigned int u[4]; short8 s; };

static __device__ __forceinline__ unsigned int f2bf(float f) {
    union { float f; unsigned int u; } v; v.f = f;
    unsigned int r = v.u + 0x7fffu + ((v.u >> 16) & 1u);
    return r >> 16;
}

// ---------------------------------------------------------------------------
// Kernel 0: W [50,1024] f32 -> Wbf [64,1024] bf16 (rows 50..63 zero), rounded.
// ---------------------------------------------------------------------------
__global__ __launch_bounds__(256) void wconv(
    const float* __restrict__ W, unsigned short* __restrict__ Wbf)
{
    int i = blockIdx.x * 256 + threadIdx.x;   // 0..65535
    int r = i >> 10, c = i & 1023;
    float v = (r < LBL) ? W[r * DD + c] : 0.f;
    Wbf[i] = (unsigned short)f2bf(v);
}

// ---------------------------------------------------------------------------
// Kernel 1: PEp[r, c] = exp(sum_d A[r,d]*W[c,d] + b[c]) for c<50, else 0.
// ---------------------------------------------------------------------------
__global__ __launch_bounds__(256) void gemm_pe(
    const float* __restrict__ A,            // [65536,1024]
    const unsigned short* __restrict__ Wbf, // [64,1024] bf16
    const float* __restrict__ bias,         // [50]
    float* __restrict__ PEp)                // [65536,64]
{
    const int tid  = threadIdx.x;
    const int lane = tid & 63;
    const int wv   = tid >> 6;
    const int mrow = lane & 15;
    const int quad = lane >> 4;
    const int row  = blockIdx.x * 64 + wv * 16 + mrow;

    const uint4* arow = (const uint4*)(A + (size_t)row * DD);

    float4v acc[4];
#pragma unroll
    for (int i = 0; i < 4; ++i) acc[i] = (float4v){0.f, 0.f, 0.f, 0.f};

#pragma unroll 4
    for (int kc = 0; kc < DD; kc += 32) {
        uint4 u0 = arow[(kc >> 2) + quad * 2];
        uint4 u1 = arow[(kc >> 2) + quad * 2 + 1];
        S8U a;
        a.u[0] = __builtin_amdgcn_perm(u0.y, u0.x, 0x07060302u);
        a.u[1] = __builtin_amdgcn_perm(u0.w, u0.z, 0x07060302u);
        a.u[2] = __builtin_amdgcn_perm(u1.y, u1.x, 0x07060302u);
        a.u[3] = __builtin_amdgcn_perm(u1.w, u1.z, 0x07060302u);
#pragma unroll
        for (int nt = 0; nt < 4; ++nt) {
            short8 bf = *(const short8*)(Wbf + (size_t)(nt * 16 + mrow) * DD + kc + quad * 8);
            acc[nt] = __builtin_amdgcn_mfma_f32_16x16x32_bf16(a.s, bf, acc[nt], 0, 0, 0);
        }
    }
    const int r0 = blockIdx.x * 64 + wv * 16 + quad * 4;
#pragma unroll
    for (int nt = 0; nt < 4; ++nt) {
        int col = nt * 16 + mrow;
        float bv = (col < LBL) ? bias[col] : 0.f;
#pragma unroll
        for (int rr = 0; rr < 4; ++rr) {
            float val = (col < LBL) ? __builtin_amdgcn_exp2f((acc[nt][rr] + bv) * L2E) : 0.f;
            PEp[(size_t)(r0 + rr) * 64 + col] = val;
        }
    }
}

// ---------------------------------------------------------------------------
// Kernel 2: segment matrix products, COLUMN-SPLIT 4x (R4).
// Block (s,k) has 4 waves; wave c owns columns [c*16, c*16+16) of
// M = Prod G~_t (column blocks evolve independently: M[:,n] <- G~ M[:,n]).
// Per wave per step: 8 MFMA + ~50 VALU, chain ~150cy; ~105 VGPR ->
// launch_bounds(256,4) = 4 waves/SIMD (vs 1-wave blocks @2/SIMD in R3).
// Per-wave (per-column-block) power-of-2 rescale; sigma stored per (sk,c).
// The 4 waves load identical PE rows -> L1-shared.
// Output: segm[sk][n][j] = M[j][n] bf16 (B-frag-natural), segc[sk][c].
// ---------------------------------------------------------------------------
__global__ __launch_bounds__(256, 4) void crf_seg(
    const float* __restrict__ PE,      // [65536,64]
    const float* __restrict__ T,       // [52,52]
    const int*   __restrict__ lens,    // [128]
    unsigned short* __restrict__ segm, // [2048][64][64] bf16
    int* __restrict__ segc)            // [2048][4]
{
    const int sk   = blockIdx.x;
    const int s    = sk >> 4;
    const int k    = sk & 15;
    const int tid  = threadIdx.x;
    const int lane = tid & 63;
    const int c    = tid >> 6;        // column block 0..3
    const int b    = lane & 15;
    const int q    = lane >> 4;
    const int L    = lens[s];
    const int t0   = 1 + k * 32;
    int tend = t0 + 31; if (L - 1 < tend) tend = L - 1;   // inclusive

    // constant A-frags: sigma-permuted e^T (R1-verified)
    short8 afr[4][2];
#pragma unroll
    for (int it = 0; it < 4; ++it) {
        int i = (b >> 2) * 8 + (b & 3) + 4 * (it & 1) + 32 * (it >> 1);
#pragma unroll
        for (int jt = 0; jt < 2; ++jt) {
            S8U pk;
#pragma unroll
            for (int h = 0; h < 4; ++h) {
                int k0 = jt * 32 + q * 8 + 2 * h;
                float v0 = (i < NL && k0     < NL) ? __builtin_amdgcn_exp2f(T[i * NL + k0]     * L2E) : 0.f;
                float v1 = (i < NL && k0 + 1 < NL) ? __builtin_amdgcn_exp2f(T[i * NL + k0 + 1] * L2E) : 0.f;
                pk.u[h] = f2bf(v0) | (f2bf(v1) << 16);
            }
            afr[it][jt] = pk.s;
        }
    }

    // M-block = I columns: bfr[kc].u[u] holds M[kk][n], kk=kc*32+q*8+2u(+1),
    // n = c*16+b.
    S8U bfr[2];
#pragma unroll
    for (int kc = 0; kc < 2; ++kc)
#pragma unroll
        for (int u = 0; u < 4; ++u) {
            int kk = kc * 32 + q * 8 + 2 * u;
            int n  = c * 16 + b;
            unsigned int v = 0;
            if (kk == n)     v |= 0x3F80u;
            if (kk + 1 == n) v |= (0x3F80u << 16);
            bfr[kc].u[u] = v;
        }

    int csum = 0;
    const float* prow = PE + (size_t)(s * SS + t0) * 64 + q * 8;
    for (int t = t0; t <= tend; ++t) {
        // PE row for the diag: issued first, consumed after the MFMAs
        float4 f0 = *(const float4*)(prow);
        float4 f1 = *(const float4*)(prow + 4);
        float4 f2 = *(const float4*)(prow + 32);
        float4 f3 = *(const float4*)(prow + 36);

        const float4v zz = (float4v){0.f, 0.f, 0.f, 0.f};
        float4v acc[4];
#pragma unroll
        for (int it = 0; it < 4; ++it)
            acc[it] = __builtin_amdgcn_mfma_f32_16x16x32_bf16(afr[it][0], bfr[0].s, zz, 0, 0, 0);
#pragma unroll
        for (int it = 0; it < 4; ++it)
            acc[it] = __builtin_amdgcn_mfma_f32_16x16x32_bf16(afr[it][1], bfr[1].s, acc[it], 0, 0, 0);

        // per-wave (per-column-block) power-of-2 rescale
        int myeb = (int)((__float_as_uint(acc[0][0]) >> 23) & 0xffu);
        int eb   = __builtin_amdgcn_readfirstlane(myeb);
        float ss = __uint_as_float((unsigned int)(254 - eb) << 23); // 2^(127-eb)
        csum += 127 - eb;

        float pvs[16];
        pvs[0]  = f0.x * ss; pvs[1]  = f0.y * ss; pvs[2]  = f0.z * ss; pvs[3]  = f0.w * ss;
        pvs[4]  = f1.x * ss; pvs[5]  = f1.y * ss; pvs[6]  = f1.z * ss; pvs[7]  = f1.w * ss;
        pvs[8]  = f2.x * ss; pvs[9]  = f2.y * ss; pvs[10] = f2.z * ss; pvs[11] = f2.w * ss;
        pvs[12] = f3.x * ss; pvs[13] = f3.y * ss; pvs[14] = f3.z * ss; pvs[15] = f3.w * ss;

        float ev[16];
#pragma unroll
        for (int kp = 0; kp < 16; ++kp)
            ev[kp] = acc[kp >> 2][kp & 3] * pvs[kp];
#pragma unroll
        for (int kc = 0; kc < 2; ++kc)
#pragma unroll
            for (int u = 0; u < 4; ++u)
                bfr[kc].u[u] = __builtin_amdgcn_perm(
                    __float_as_uint(ev[kc * 8 + 2 * u + 1]),
                    __float_as_uint(ev[kc * 8 + 2 * u]), 0x07060302u);

        prow += 64;
    }

    // store: segm[sk][n][j] = M[j][n], n = c*16+b, j = kc*32+q*8+(0..7)
    unsigned short* ob = segm + (size_t)sk * 4096;
#pragma unroll
    for (int kc = 0; kc < 2; ++kc) {
        uint4 st; st.x = bfr[kc].u[0]; st.y = bfr[kc].u[1];
        st.z = bfr[kc].u[2]; st.w = bfr[kc].u[3];
        *(uint4*)(ob + (c * 16 + b) * 64 + kc * 32 + q * 8) = st;
    }
    if (lane == 0) segc[sk * 4 + c] = csum;
}

// ---------------------------------------------------------------------------
// Kernel 3: fold + gold + loss. 1 block/seq, wave0 fold, wave1 gold.
// R4: per-column-block scales (m_c = Fw + sigma_c); common anchor Fnew from
// cross-lane max of true exponents; per-block pow2 multiplier (2-way split,
// <=127 provable, underflow->0 correct). Loads software-pipelined 1 ahead.
// ---------------------------------------------------------------------------
__global__ __launch_bounds__(128) void crf_comb(
    const float* __restrict__ PE,
    const float* __restrict__ T,
    const int*   __restrict__ lens,
    const int*   __restrict__ labels,
    const unsigned short* __restrict__ segm,
    const int*   __restrict__ segc,
    float* __restrict__ out)
{
    const int s    = blockIdx.x;
    const int tid  = threadIdx.x;
    const int lane = tid & 63;
    const int wv   = tid >> 6;

    __shared__ float gold_sh;
    float norm_ln = 0.f;

    if (wv == 1) {
        const int len = lens[s];
        const size_t base = (size_t)s * SS;
        float un2 = 0.f, bi = 0.f;
        for (int t = lane; t < len; t += 64) {
            int lab  = labels[base + t];
            int prev = (t == 0) ? LBL : labels[base + t - 1];
            un2 += __builtin_amdgcn_logf(PE[(base + t) * 64 + lab]); // log2
            bi  += T[lab * NL + prev];
        }
        float g = un2 * (1.0f / L2E) + bi;
        g += __shfl_xor(g, 1, 64);
        g += __shfl_xor(g, 2, 64);
        g += __shfl_xor(g, 4, 64);
        g += __shfl_xor(g, 8, 64);
        g += __shfl_xor(g, 16, 64);
        g += __shfl_xor(g, 32, 64);
        if (lane == 0) {
            g += T[(NL - 1) * NL + labels[base + len - 1]];
            gold_sh = g;
        }
    } else {
        const int b = lane & 15, q = lane >> 4;
        const float4v zz = (float4v){0.f, 0.f, 0.f, 0.f};

        // w0 A-frags (rows replicated): aw[kc] = w[kc*32+q*8+(0..7)]
        S8U aw[2];
#pragma unroll
        for (int kc = 0; kc < 2; ++kc)
#pragma unroll
            for (int u = 0; u < 4; ++u) {
                int j0 = kc * 32 + q * 8 + 2 * u;
                float v0 = (j0     < NL) ? __builtin_amdgcn_exp2f(T[(NL - 1) * NL + j0]     * L2E) : 0.f;
                float v1 = (j0 + 1 < NL) ? __builtin_amdgcn_exp2f(T[(NL - 1) * NL + j0 + 1] * L2E) : 0.f;
                aw[kc].u[u] = f2bf(v0) | (f2bf(v1) << 16);
            }

        int Fw = 0;
        float sv[4] = {0.f, 0.f, 0.f, 0.f};

        S8U bufA[4][2], bufB[4][2];
        int scA[4], scB[4];

#define LOADSEG(BUF, SC, KK) do {                                                 \
        const unsigned short* mb = segm + (size_t)(s * 16 + (KK)) * 4096;         \
        _Pragma("unroll")                                                         \
        for (int nt = 0; nt < 4; ++nt)                                            \
            _Pragma("unroll")                                                     \
            for (int kc = 0; kc < 2; ++kc) {                                      \
                uint4 ld = *(const uint4*)(mb + (nt * 16 + b) * 64 + kc * 32 + q * 8); \
                BUF[nt][kc].u[0] = ld.x; BUF[nt][kc].u[1] = ld.y;                 \
                BUF[nt][kc].u[2] = ld.z; BUF[nt][kc].u[3] = ld.w;                 \
            }                                                                     \
        int4 s4 = *(const int4*)(segc + (s * 16 + (KK)) * 4);                     \
        SC[0] = s4.x; SC[1] = s4.y; SC[2] = s4.z; SC[3] = s4.w;                   \
    } while (0)

#define FOLD(BUF, SC, KK) do {                                                    \
        float4v acc[4];                                                           \
        _Pragma("unroll")                                                         \
        for (int nt = 0; nt < 4; ++nt)                                            \
            acc[nt] = __builtin_amdgcn_mfma_f32_16x16x32_bf16(aw[0].s, BUF[nt][0].s, zz, 0, 0, 0); \
        _Pragma("unroll")                                                         \
        for (int nt = 0; nt < 4; ++nt)                                            \
            acc[nt] = __builtin_amdgcn_mfma_f32_16x16x32_bf16(aw[1].s, BUF[nt][1].s, acc[nt], 0, 0, 0); \
        int mm[4], te[4];                                                         \
        _Pragma("unroll")                                                         \
        for (int nt = 0; nt < 4; ++nt) {                                          \
            mm[nt] = Fw + SC[nt];                                                 \
            unsigned bt = __float_as_uint(acc[nt][0]);                            \
            int ebf = (int)((bt >> 23) & 255u);                                   \
            te[nt] = (acc[nt][0] == 0.f) ? (int)0xC1000000 : (ebf - 127 - mm[nt]);\
        }                                                                         \
        int tm = te[0]; tm = (te[1] > tm) ? te[1] : tm;                           \
        tm = (te[2] > tm) ? te[2] : tm; tm = (te[3] > tm) ? te[3] : tm;           \
        tm = max(tm, __shfl_xor(tm, 1, 64));                                      \
        tm = max(tm, __shfl_xor(tm, 2, 64));                                      \
        tm = max(tm, __shfl_xor(tm, 4, 64));                                      \
        tm = max(tm, __shfl_xor(tm, 8, 64));                                      \
        int Fnew = -tm;                                                           \
        _Pragma("unroll")                                                         \
        for (int nt = 0; nt < 4; ++nt) {                                          \
            int e_m = Fnew - mm[nt];                                              \
            int h1 = e_m >> 1; int h2 = e_m - h1;                                 \
            float m1 = __uint_as_float((unsigned)(h1 + 127) << 23);               \
            float m2 = __uint_as_float((unsigned)(h2 + 127) << 23);               \
            sv[nt] = (e_m < -252) ? 0.f : acc[nt][0] * m1 * m2;                   \
        }                                                                         \
        Fw = Fnew;                                                                \
        if ((KK) > 0) {                                                           \
            float svq = (q & 2) ? ((q & 1) ? sv[3] : sv[2])                       \
                                : ((q & 1) ? sv[1] : sv[0]);                      \
            int svqi = __float_as_int(svq);                                       \
            _Pragma("unroll")                                                     \
            for (int kc = 0; kc < 2; ++kc)                                        \
                _Pragma("unroll")                                                 \
                for (int u = 0; u < 4; ++u) {                                     \
                    int j0 = kc * 32 + q * 8 + 2 * u;                             \
                    int w0i = __builtin_amdgcn_ds_bpermute(j0 * 4,       svqi);   \
                    int w1i = __builtin_amdgcn_ds_bpermute((j0 + 1) * 4, svqi);   \
                    aw[kc].u[u] = __builtin_amdgcn_perm((unsigned)w1i, (unsigned)w0i, 0x07060302u); \
                }                                                                 \
        }                                                                         \
    } while (0)

        LOADSEG(bufA, scA, 15);
        for (int kp = 0; kp < 8; ++kp) {
            int kk = 15 - 2 * kp;
            if (kk >= 1) LOADSEG(bufB, scB, kk - 1);
            FOLD(bufA, scA, kk);
            if (kk >= 2) LOADSEG(bufA, scA, kk - 2);
            FOLD(bufB, scB, kk - 1);
        }
#undef FOLD
#undef LOADSEG

        // dot with E1[n] = PE[seq row 0][n] * e^{T[n][START]}
        float dp = 0.f;
        const float* pe0 = PE + (size_t)s * SS * 64;
#pragma unroll
        for (int nt = 0; nt < 4; ++nt) {
            int n = nt * 16 + b;
            float e1 = (n < NL) ? pe0[n] * __builtin_amdgcn_exp2f(T[n * NL + LBL] * L2E) : 0.f;
            dp += sv[nt] * e1;
        }
        dp += __shfl_xor(dp, 1, 64);
        dp += __shfl_xor(dp, 2, 64);
        dp += __shfl_xor(dp, 4, 64);
        dp += __shfl_xor(dp, 8, 64);
        norm_ln = (__builtin_amdgcn_logf(dp) - (float)Fw) * (1.0f / L2E);
    }

    __syncthreads();
    if (tid == 0) atomicAdd(out, norm_ln - gold_sh);
}

// ---------------------------------------------------------------------------
extern "C" void kernel_launch(void* const* d_in, const int* in_sizes, int n_in,
                              void* d_out, int out_size, void* d_ws, size_t ws_size,
                              hipStream_t stream) {
    const float* A      = (const float*)d_in[0]; // inputs [128,512,1024]
    const float* W      = (const float*)d_in[1]; // [50,1024]
    const float* bias   = (const float*)d_in[2]; // [50]
    const float* T      = (const float*)d_in[3]; // [52,52]
    const int*   lens   = (const int*)d_in[4];   // [128]
    const int*   labels = (const int*)d_in[5];   // [128,512]
    float* out = (float*)d_out;

    float* PEp = (float*)d_ws;                                              // 16.78 MB
    unsigned short* Wbf  = (unsigned short*)((char*)d_ws + (size_t)65536 * 64 * 4); // 131 KB
    unsigned short* segm = (unsigned short*)((char*)d_ws + ((size_t)32 << 20));     // 16.78 MB
    int*            segc = (int*)((char*)d_ws + ((size_t)56 << 20));                // 32 KB

    hipMemsetAsync(d_out, 0, sizeof(float), stream);
    wconv<<<dim3(256), dim3(256), 0, stream>>>(W, Wbf);
    gemm_pe<<<dim3((BB * SS) / 64), dim3(256), 0, stream>>>(A, Wbf, bias, PEp);
    crf_seg<<<dim3(2048), dim3(256), 0, stream>>>(PEp, T, lens, segm, segc);
    crf_comb<<<dim3(128), dim3(128), 0, stream>>>(PEp, T, lens, labels, segm, segc, out);
}